// Round 12
// baseline (59.903 us; speedup 1.0000x reference)
//
#include <hip/hip_runtime.h>

// CCM: causal 3x3 complex multi-frame filter.
// out[b,f,t,:] = sum_{i,j} (Hr+i*Hi)[b,i,j,t,f] * x[b, f+j-1, t+i-2, :]
// H = sum_k c_k * a_k,  c_0 = 1, c_1 = -1/2 + i*sqrt3/2, c_2 = -1/2 - i*sqrt3/2
// a_k = m[b, 9k + 3i + j, t, f]
//
// Block = one (b, 8-t chunk) as two 4-step halves (x window re-staged between
// halves; m batches for the next half issued BEFORE the mid barrier so the
// memory pipe never drains). 960 threads = 3 k-groups x 5 waves, lane = f.
// Per-step partials go straight to an LDS slab (keeps VGPR < 64 -> 2
// blocks/CU); distributed epilogue sums 3 slabs, 64 B/lane float4 stores.
// R12 = R9 with launch_bounds (960,8) -> (960,4): the 8-waves/EU bound
// clamped VGPR to 32 and spilled (R9 WRITE=40.8 MB vs 16.4 real; R10 224 MB).

constexpr int B = 8, C = 27, T = 1000, F = 257;
constexpr int TCH = 8;                // t per block tile
constexpr int NT  = T / TCH;          // 125 -> 1000 blocks
constexpr int GRP = 320;              // threads per k-group (5 waves)
constexpr int BLK = 3 * GRP;          // 960
constexpr int HROW = 6;               // staged t rows per half (u-2 .. u+3)
constexpr int RP   = 7;               // xs row pitch (odd -> conflict-free)
constexpr int PLANE = 260 * RP;       // floats per xs plane
constexpr int SLABP = 257;            // slab f-pitch (float2 units)
constexpr size_t CS = (size_t)T * F;  // m channel stride

__global__ __launch_bounds__(BLK, 4)   // VGPR headroom: batches stay live
void ccm_kernel(const float* __restrict__ m,
                const float* __restrict__ x,
                float* __restrict__ out) {
    __shared__ float  xs[2 * PLANE];          // x window: 14,560 B
    __shared__ float2 rs[3 * TCH * SLABP];    // partial slabs: 49,344 B

    const int bid = blockIdx.x;
    const int tc  = bid % NT;
    const int b   = bid / NT;
    const int t0  = tc * TCH;
    const int tx  = threadIdx.x;
    const int g   = tx / GRP;          // k-group 0..2 (wave-uniform)
    const int f   = tx - g * GRP;      // lane-in-group = f (0..319)
    const bool active = (f < F);

    const float* xb = x + (size_t)b * F * T * 2;

    // ---- group constants: c_k ----
    const float SQ3_2 = 0.8660254037844386f;
    const float ckr = (g == 0) ? 1.0f : -0.5f;
    const float cki = (g == 0) ? 0.0f : ((g == 1) ? SQ3_2 : -SQ3_2);

    const float* mb = m + (((size_t)b * C + 9 * g) * T + t0) * F;

    float Am[9], Bm[9];
    float wr[3][3], wi[3][3];

    // stage x rows tb..tb+5 (re/im planes), all 960 threads
    auto stage = [&](int tb) {
        for (int p = tx; p < 259 * HROW; p += BLK) {
            const int row = p / HROW;          // 0..258
            const int tt  = p - row * HROW;    // 0..5
            const int ff  = row - 1;           // -1..257
            const int t   = tb + tt;
            float re = 0.f, im = 0.f;
            if (ff >= 0 && ff < F && t >= 0) {
                const float2 v = *reinterpret_cast<const float2*>(
                    xb + ((size_t)ff * T + t) * 2);
                re = v.x; im = v.y;
            }
            xs[row * RP + tt]         = re;
            xs[PLANE + row * RP + tt] = im;
        }
    };

// 9-load batch for t-step S into named register array DST (static idx)
#define LOADM(DST, S)                                                     \
    {                                                                     \
        _Pragma("unroll")                                                 \
        for (int n = 0; n < 9; ++n)                                       \
            DST[n] = mb[(size_t)n * CS + (size_t)(S) * F + f];            \
    }

// consume batch AV for global step S (slab row), local step U (tt = U+2)
#define STEP(AV, S, U)                                                    \
    {                                                                     \
        _Pragma("unroll")                                                 \
        for (int j = 0; j < 3; ++j) {                                     \
            const float xr = xs[(f + j) * RP + ((U) + 2)];                \
            const float xi = xs[PLANE + (f + j) * RP + ((U) + 2)];        \
            wr[2][j] = ckr * xr - cki * xi;                               \
            wi[2][j] = ckr * xi + cki * xr;                               \
        }                                                                 \
        float accr = 0.f, acci = 0.f;                                     \
        _Pragma("unroll")                                                 \
        for (int i = 0; i < 3; ++i) {                                     \
            _Pragma("unroll")                                             \
            for (int j = 0; j < 3; ++j) {                                 \
                const int n = i * 3 + j;                                  \
                accr += AV[n] * wr[i][j];                                 \
                acci += AV[n] * wi[i][j];                                 \
            }                                                             \
        }                                                                 \
        rs[g * (TCH * SLABP) + (S) * SLABP + f] = make_float2(accr, acci);\
        _Pragma("unroll")                                                 \
        for (int j = 0; j < 3; ++j) {                                     \
            wr[0][j] = wr[1][j]; wi[0][j] = wi[1][j];                     \
            wr[1][j] = wr[2][j]; wi[1][j] = wi[2][j];                     \
        }                                                                 \
    }

    // prologue m batches in flight before any barrier (independent of xs)
    if (active) {
        LOADM(Am, 0);
        LOADM(Bm, 1);
    }
    stage(t0 - 2);                     // half A: rows t0-2 .. t0+3
    __syncthreads();

    if (active) {
        // init window rows t0-2, t0-1 (tt = 0, 1)
        #pragma unroll
        for (int p = 0; p < 2; ++p) {
            #pragma unroll
            for (int j = 0; j < 3; ++j) {
                const float xr = xs[(f + j) * RP + p];
                const float xi = xs[PLANE + (f + j) * RP + p];
                wr[p][j] = ckr * xr - cki * xi;
                wi[p][j] = ckr * xi + cki * xr;
            }
        }
        STEP(Am, 0, 0);  LOADM(Am, 2);
        STEP(Bm, 1, 1);  LOADM(Bm, 3);
        STEP(Am, 2, 2);  LOADM(Am, 4);   // steps 4,5 batches in flight
        STEP(Bm, 3, 3);  LOADM(Bm, 5);   // across the stage-B phase
    }
    __syncthreads();                   // xs half-A reads done

    stage(t0 + 2);                     // half B: rows t0+2 .. t0+7
    __syncthreads();

    if (active) {
        STEP(Am, 4, 0);  LOADM(Am, 6);
        STEP(Bm, 5, 1);  LOADM(Bm, 7);
        STEP(Am, 6, 2);
        STEP(Bm, 7, 3);
    }
#undef LOADM
#undef STEP
    __syncthreads();                   // slab writes visible

    // ---- store phase: sum 3 slabs, 16 B tasks -> 64 B/lane-quad lines ----
    for (int task = tx; task < F * 4; task += BLK) {
        const int ff = task >> 2;          // output f row
        const int q  = task & 3;           // t-pair index (2 t per float4)
        float4 o = make_float4(0.f, 0.f, 0.f, 0.f);
        #pragma unroll
        for (int gg = 0; gg < 3; ++gg) {
            const float2 p0 = rs[gg * (TCH * SLABP) + (2 * q) * SLABP + ff];
            const float2 p1 = rs[gg * (TCH * SLABP) + (2 * q + 1) * SLABP + ff];
            o.x += p0.x; o.y += p0.y; o.z += p1.x; o.w += p1.y;
        }
        *reinterpret_cast<float4*>(
            out + ((size_t)(b * F + ff) * T + t0) * 2 + q * 4) = o;
    }
}

extern "C" void kernel_launch(void* const* d_in, const int* in_sizes, int n_in,
                              void* d_out, int out_size, void* d_ws, size_t ws_size,
                              hipStream_t stream) {
    const float* m = (const float*)d_in[0];
    const float* x = (const float*)d_in[1];
    // d_in[2] = v is a fixed compile-time constant per the reference.
    float* out = (float*)d_out;

    const int grid = B * NT;               // 1000 blocks
    ccm_kernel<<<grid, BLK, 0, stream>>>(m, x, out);
}

// Round 13
// 58.978 us; speedup vs baseline: 1.0157x; 1.0157x over previous
//
#include <hip/hip_runtime.h>

// CCM: causal 3x3 complex multi-frame filter.
// out[b,f,t,:] = sum_{i,j} (Hr+i*Hi)[b,i,j,t,f] * x[b, f+j-1, t+i-2, :]
// H = sum_k c_k * a_k,  c_0 = 1, c_1 = -1/2 + i*sqrt3/2, c_2 = -1/2 - i*sqrt3/2
// a_k = m[b, 9k + 3i + j, t, f]
//
// Block = one (b, 4-t chunk), 960 threads = 3 k-groups x 5 waves (lane = f).
// Each group streams its 9 channels as double-buffered 9-load register
// batches, folds c_k into its x-window taps, partials reduced through LDS.
// R13 = R11 + real cross-barrier m prefetch:
//  - x window staged in ONE dwordx4 round (777 aligned float4 tasks),
//    loads split from LDS writes (issue-early / write-late),
//  - m prologue (Am,Bm = 18 loads) issued AFTER x loads (in-order vmcnt:
//    ds_write waits only on x) and BEFORE the barrier,
//  - first barrier = lgkmcnt(0)-only + raw s_barrier (no vmcnt drain!)
//    so the 18 m loads stay in flight across it. __syncthreads would
//    drain vmcnt(0) and expose full HBM latency per block (m97 note).

constexpr int B = 8, C = 27, T = 1000, F = 257;
constexpr int TCH = 4;               // t per block tile
constexpr int NT  = T / TCH;         // 250 -> 2000 blocks
constexpr int GRP = 320;             // threads per k-group (5 waves)
constexpr int BLK = 3 * GRP;         // 960
constexpr int ROWSU = 259;           // x rows used: f = -1..257 (row = f+1)
constexpr int RP    = 7;             // odd row pitch -> conflict-free reads
constexpr int PLANE = 260 * RP;      // dwords per x plane
constexpr int RPITCH = 260;          // reduce-slab f pitch
constexpr int STASK = ROWSU * 3;     // 777 staging tasks (row, t-pair)

__global__ __launch_bounds__(BLK, 4)   // VGPR headroom for live batches
void ccm_kernel(const float* __restrict__ m,
                const float* __restrict__ x,
                float* __restrict__ out) {
    __shared__ float xs[2 * PLANE];              // x window: 14.6 KB
    __shared__ float rs[2 * TCH * RPITCH * 2];   // partial slabs g=1,2: 16.6 KB

    const int bid = blockIdx.x;
    const int tc  = bid % NT;
    const int b   = bid / NT;
    const int t0  = tc * TCH;
    const int tx  = threadIdx.x;
    const int g   = tx / GRP;          // k-group 0..2 (wave-uniform)
    const int f   = tx - g * GRP;      // lane-in-group = f (0..319)
    const bool active = (f < F);

    const float* xb = x + (size_t)b * F * T * 2;

    // ---- x-stage, phase 1: issue loads (one dwordx4 round, 777 tasks) ----
    // task = q*259 + row: row 0..258 (f = row-1), q 0..2 (t = t0-2+2q, +1)
    const bool do_stage = (tx < STASK);
    int srow = 0, sq = 0;
    float4 xv = make_float4(0.f, 0.f, 0.f, 0.f);
    if (do_stage) {
        sq   = tx / ROWSU;                 // 0..2
        srow = tx - sq * ROWSU;            // 0..258
        const int ff = srow - 1;
        const int tq = t0 - 2 + 2 * sq;
        if (ff >= 0 && ff < F && tq >= 0) {
            // (ff*T + tq) even and *8B -> 16B aligned always
            xv = *reinterpret_cast<const float4*>(
                xb + ((size_t)ff * T + tq) * 2);
        }
    }

    // ---- group constants: c_k ----
    const float SQ3_2 = 0.8660254037844386f;
    const float ckr = (g == 0) ? 1.0f : -0.5f;
    const float cki = (g == 0) ? 0.0f : ((g == 1) ? SQ3_2 : -SQ3_2);

    constexpr size_t CS = (size_t)T * F;   // m channel stride
    const float* mb = m + (((size_t)b * C + 9 * g) * T + t0) * F;

    float2 res[TCH];
    float Am[9], Bm[9];
    float wr[3][3], wi[3][3];

// 9-load batch for t-step U into named register array DST (static idx)
#define LOADM(DST, U)                                                     \
    {                                                                     \
        _Pragma("unroll")                                                 \
        for (int n = 0; n < 9; ++n)                                       \
            DST[n] = mb[(size_t)n * CS + (size_t)(U) * F + f];            \
    }

// consume batch AV for t-step U: refresh transformed window row 2, 9 MACs
#define STEP(AV, U)                                                       \
    {                                                                     \
        _Pragma("unroll")                                                 \
        for (int j = 0; j < 3; ++j) {                                     \
            const float xr = xs[(f + j) * RP + ((U) + 2)];                \
            const float xi = xs[PLANE + (f + j) * RP + ((U) + 2)];        \
            wr[2][j] = ckr * xr - cki * xi;                               \
            wi[2][j] = ckr * xi + cki * xr;                               \
        }                                                                 \
        float accr = 0.f, acci = 0.f;                                     \
        _Pragma("unroll")                                                 \
        for (int i = 0; i < 3; ++i) {                                     \
            _Pragma("unroll")                                             \
            for (int j = 0; j < 3; ++j) {                                 \
                const int n = i * 3 + j;                                  \
                accr += AV[n] * wr[i][j];                                 \
                acci += AV[n] * wi[i][j];                                 \
            }                                                             \
        }                                                                 \
        res[U] = make_float2(accr, acci);                                 \
        _Pragma("unroll")                                                 \
        for (int j = 0; j < 3; ++j) {                                     \
            wr[0][j] = wr[1][j]; wi[0][j] = wi[1][j];                     \
            wr[1][j] = wr[2][j]; wi[1][j] = wi[2][j];                     \
        }                                                                 \
    }

    // ---- m prologue: issued AFTER x loads (in-order vmcnt -> the x
    // ds_writes below wait only for x), BEFORE the barrier ----
    if (active) {
        LOADM(Am, 0);
        LOADM(Bm, 1);
    }

    // ---- x-stage, phase 2: LDS writes (wait on x loads only) ----
    if (do_stage) {
        const int a = srow * RP + 2 * sq;
        xs[a]             = xv.x;          // re(t)
        xs[a + 1]         = xv.z;          // re(t+1)
        xs[PLANE + a]     = xv.y;          // im(t)
        xs[PLANE + a + 1] = xv.w;          // im(t+1)
    }

    // ---- barrier WITHOUT vmcnt drain: m loads stay in flight ----
    asm volatile("s_waitcnt lgkmcnt(0)" ::: "memory");
    __builtin_amdgcn_s_barrier();

    if (active) {
        // init transformed window rows t0-2, t0-1
        #pragma unroll
        for (int p = 0; p < 2; ++p) {
            #pragma unroll
            for (int j = 0; j < 3; ++j) {
                const float xr = xs[(f + j) * RP + p];
                const float xi = xs[PLANE + (f + j) * RP + p];
                wr[p][j] = ckr * xr - cki * xi;
                wi[p][j] = ckr * xi + cki * xr;
            }
        }

        STEP(Am, 0);  LOADM(Am, 2);
        STEP(Bm, 1);  LOADM(Bm, 3);
        STEP(Am, 2);
        STEP(Bm, 3);

        // groups 1,2 deposit partials into LDS slabs
        if (g > 0) {
            float2* slab = reinterpret_cast<float2*>(rs) +
                           (size_t)(g - 1) * TCH * RPITCH;
            #pragma unroll
            for (int r = 0; r < TCH; ++r)
                slab[r * RPITCH + f] = res[r];
        }
    }
#undef LOADM
#undef STEP

    __syncthreads();

    // ---- group 0 reduces and stores 32 B/lane contiguous ----
    if (g == 0 && active) {
        const float2* s1 = reinterpret_cast<const float2*>(rs);
        const float2* s2 = s1 + (size_t)TCH * RPITCH;
        #pragma unroll
        for (int r = 0; r < TCH; ++r) {
            const float2 p1 = s1[r * RPITCH + f];
            const float2 p2 = s2[r * RPITCH + f];
            res[r].x += p1.x + p2.x;
            res[r].y += p1.y + p2.y;
        }
        float* op = out + ((size_t)(b * F + f) * T + t0) * 2;
        #pragma unroll
        for (int u = 0; u < TCH / 2; ++u) {
            reinterpret_cast<float4*>(op)[u] =
                make_float4(res[2 * u].x, res[2 * u].y,
                            res[2 * u + 1].x, res[2 * u + 1].y);
        }
    }
}

extern "C" void kernel_launch(void* const* d_in, const int* in_sizes, int n_in,
                              void* d_out, int out_size, void* d_ws, size_t ws_size,
                              hipStream_t stream) {
    const float* m = (const float*)d_in[0];
    const float* x = (const float*)d_in[1];
    // d_in[2] = v is a fixed compile-time constant per the reference.
    float* out = (float*)d_out;

    const int grid = B * NT;               // 2000 blocks
    ccm_kernel<<<grid, BLK, 0, stream>>>(m, x, out);
}